// Round 1
// baseline (3550.839 us; speedup 1.0000x reference)
//
#include <hip/hip_runtime.h>

#define DFEAT 32

// Pass 1: scatter-add half-edge features + valence counts.
// 8 lanes per half-edge row; each lane reads one float4 (coalesced 128B/row)
// and issues 4 global atomicAdds into the vertex bin.
__global__ void he2v_scatter(const float* __restrict__ x,
                             const int* __restrict__ ids,
                             float* __restrict__ out,
                             float* __restrict__ val,
                             int n_he) {
    long tid = (long)blockIdx.x * blockDim.x + threadIdx.x;
    long stride = (long)gridDim.x * blockDim.x;
    long total = (long)n_he * 8;  // 8 float4-lanes per row
    for (long t = tid; t < total; t += stride) {
        int row = (int)(t >> 3);
        int q   = (int)(t & 7);
        int v   = ids[row];
        float4 xv = ((const float4*)x)[(long)row * 8 + q];
        float* dst = out + (long)v * DFEAT + q * 4;
        atomicAdd(dst + 0, xv.x);
        atomicAdd(dst + 1, xv.y);
        atomicAdd(dst + 2, xv.z);
        atomicAdd(dst + 3, xv.w);
        if (q == 0) atomicAdd(val + v, 1.0f);
    }
}

// Pass 2: out[v][:] /= max(valence[v], 1)
__global__ void he2v_divide(float* __restrict__ out,
                            const float* __restrict__ val,
                            int n_v) {
    long tid = (long)blockIdx.x * blockDim.x + threadIdx.x;
    long total = (long)n_v * 8;  // float4 groups
    if (tid >= total) return;
    int v = (int)(tid >> 3);
    float s = val[v];
    if (s < 1.0f) s = 1.0f;
    float4 o = ((float4*)out)[tid];
    o.x /= s; o.y /= s; o.z /= s; o.w /= s;
    ((float4*)out)[tid] = o;
}

extern "C" void kernel_launch(void* const* d_in, const int* in_sizes, int n_in,
                              void* d_out, int out_size, void* d_ws, size_t ws_size,
                              hipStream_t stream) {
    const float* x  = (const float*)d_in[0];
    const int* ids  = (const int*)d_in[1];
    int n_he = in_sizes[0] / DFEAT;
    int n_v  = out_size / DFEAT;

    float* out = (float*)d_out;
    float* val = (float*)d_ws;  // n_v floats of scratch for valence

    hipMemsetAsync(out, 0, (size_t)out_size * sizeof(float), stream);
    hipMemsetAsync(val, 0, (size_t)n_v * sizeof(float), stream);

    // Scatter: grid-stride, saturate 256 CUs
    he2v_scatter<<<8192, 256, 0, stream>>>(x, ids, out, val, n_he);

    // Divide: one thread per float4
    long total = (long)n_v * 8;
    int blocks = (int)((total + 255) / 256);
    he2v_divide<<<blocks, 256, 0, stream>>>(out, val, n_v);
}